// Round 1
// baseline (2123.276 us; speedup 1.0000x reference)
//
#include <hip/hip_runtime.h>
#include <hip/hip_bf16.h>
#include <stdint.h>

#define B_ 2
#define T_ 2048
#define E_ 2048
#define H_ 16
#define HKV_ 8
#define DH_ 128
#define WINDOW_ 512

typedef unsigned short ush;
typedef float f32x4 __attribute__((ext_vector_type(4)));
typedef __bf16 bf16x8 __attribute__((ext_vector_type(8)));

static __device__ __forceinline__ ush f2bf(float f) {
    uint32_t u = __float_as_uint(f);
    uint32_t r = (u + 0x7fffu + ((u >> 16) & 1u)) >> 16;
    return (ush)r;
}
static __device__ __forceinline__ float bf2f(ush h) {
    return __uint_as_float(((uint32_t)h) << 16);
}

// ---------------- fp32 -> bf16 cast (vectorized) ----------------
__global__ __launch_bounds__(256) void cast_kernel(const float* __restrict__ in,
                                                   ush* __restrict__ out, int n4) {
    int i = blockIdx.x * blockDim.x + threadIdx.x;
    if (i >= n4) return;
    float4 f = reinterpret_cast<const float4*>(in)[i];
    ushort4 o;
    o.x = f2bf(f.x); o.y = f2bf(f.y); o.z = f2bf(f.z); o.w = f2bf(f.w);
    reinterpret_cast<ushort4*>(out)[i] = o;
}

// ---------------- bf16 GEMM, C = A * B^T  (A:[M][K], Bm:[N][K]) ----------------
// MODE 0: scatter store bf16 into q/k/v layouts ([B][H][T][DH] / [B][HKV][T][DH])
// MODE 1: store fp32 row-major C[M][N]
template <int MODE>
__global__ __launch_bounds__(256, 2) void gemm_bt(
    const ush* __restrict__ A, const ush* __restrict__ Bm,
    float* __restrict__ Cf, ush* __restrict__ q, ush* __restrict__ k, ush* __restrict__ v,
    int M, int N, int K)
{
    __shared__ ush As[128 * 64];
    __shared__ ush Bs[128 * 64];
    const int tid = threadIdx.x;
    const int lane = tid & 63;
    const int wid = tid >> 6;           // 0..3
    const int wr = wid >> 1, wc = wid & 1;
    const int gm0 = blockIdx.x * 128, gn0 = blockIdx.y * 128;

    f32x4 acc[4][4] = {};

    const int l8 = lane >> 3;           // 0..7 (row within 8-row staging group)
    const int ce = (lane & 7) * 8;      // element offset within row (8 ush = 16B)

    for (int kt = 0; kt < K; kt += 64) {
#pragma unroll
        for (int i = 0; i < 4; ++i) {
            const int rowbase = (i * 4 + wid) * 8;     // wave-uniform
            const int ra = rowbase + l8;
            const ush* ga = A + (size_t)(gm0 + ra) * K + kt + ce;
            __builtin_amdgcn_global_load_lds(
                (const __attribute__((address_space(1))) void*)ga,
                (__attribute__((address_space(3))) void*)(As + rowbase * 64), 16, 0, 0);
            const ush* gb = Bm + (size_t)(gn0 + ra) * K + kt + ce;
            __builtin_amdgcn_global_load_lds(
                (const __attribute__((address_space(1))) void*)gb,
                (__attribute__((address_space(3))) void*)(Bs + rowbase * 64), 16, 0, 0);
        }
        __syncthreads();   // drains vmcnt (global_load_lds) + lgkm before barrier

#pragma unroll
        for (int s = 0; s < 2; ++s) {
            bf16x8 aF[4], bF[4];
#pragma unroll
            for (int mm = 0; mm < 4; ++mm) {
                int r = wr * 64 + mm * 16 + (lane & 15);
                aF[mm] = *reinterpret_cast<const bf16x8*>(As + r * 64 + s * 32 + ((lane >> 4) * 8));
            }
#pragma unroll
            for (int nn = 0; nn < 4; ++nn) {
                int r = wc * 64 + nn * 16 + (lane & 15);
                bF[nn] = *reinterpret_cast<const bf16x8*>(Bs + r * 64 + s * 32 + ((lane >> 4) * 8));
            }
#pragma unroll
            for (int mm = 0; mm < 4; ++mm)
#pragma unroll
                for (int nn = 0; nn < 4; ++nn)
                    acc[mm][nn] = __builtin_amdgcn_mfma_f32_16x16x32_bf16(
                        aF[mm], bF[nn], acc[mm][nn], 0, 0, 0);
        }
        __syncthreads();
    }

    // epilogue: C/D layout col=lane&15, row=4*(lane>>4)+r  [m89/m91 verified]
    const int rsub = (lane >> 4) << 2;
    const int csub = lane & 15;
#pragma unroll
    for (int mm = 0; mm < 4; ++mm) {
        const int row0 = gm0 + wr * 64 + mm * 16 + rsub;
#pragma unroll
        for (int nn = 0; nn < 4; ++nn) {
            const int col = gn0 + wc * 64 + nn * 16 + csub;
#pragma unroll
            for (int r = 0; r < 4; ++r) {
                const int row = row0 + r;
                if (MODE == 1) {
                    Cf[(size_t)row * N + col] = acc[mm][nn][r];
                } else {
                    const int bb = row >> 11, tt = row & (T_ - 1);
                    const ush val = f2bf(acc[mm][nn][r]);
                    if (col < H_ * DH_) {
                        const int hh = col >> 7, d = col & 127;
                        q[((((size_t)bb * H_ + hh) * T_ + tt) << 7) + d] = val;
                    } else if (col < H_ * DH_ + HKV_ * DH_) {
                        const int c2 = col - H_ * DH_;
                        const int hh = c2 >> 7, d = c2 & 127;
                        k[((((size_t)bb * HKV_ + hh) * T_ + tt) << 7) + d] = val;
                    } else {
                        const int c2 = col - H_ * DH_ - HKV_ * DH_;
                        const int hh = c2 >> 7, d = c2 & 127;
                        v[((((size_t)bb * HKV_ + hh) * T_ + tt) << 7) + d] = val;
                    }
                }
            }
        }
    }
}

// ---------------- per-head RMSNorm + RoPE (+ q scale), in place ----------------
__global__ __launch_bounds__(256) void norm_rope(ush* __restrict__ q, ush* __restrict__ k,
                                                 const float* __restrict__ qw,
                                                 const float* __restrict__ kw)
{
    const int lane = threadIdx.x & 63;
    const int row = blockIdx.x * 4 + (threadIdx.x >> 6);
    const int NQ = B_ * H_ * T_;
    ush* p; const float* w; int t; bool isq = (row < NQ);
    if (isq) { p = q + ((size_t)row << 7); t = row & (T_ - 1); w = qw; }
    else     { int r2 = row - NQ; p = k + ((size_t)r2 << 7); t = r2 & (T_ - 1); w = kw; }

    float x0 = bf2f(p[lane]);
    float x1 = bf2f(p[lane + 64]);
    float ss = x0 * x0 + x1 * x1;
#pragma unroll
    for (int off = 32; off; off >>= 1) ss += __shfl_xor(ss, off);
    const float rms = rsqrtf(ss * (1.0f / 128.0f) + 1e-6f);
    float y0 = x0 * rms * (1.0f + w[lane]);
    float y1 = x1 * rms * (1.0f + w[lane + 64]);

    // inv_freq = 10000^(-lane/64) = exp(-lane * ln(10000)/64)
    const float invf = expf(-(float)lane * 0.14391156831212787f);
    const float fr = (float)t * invf;
    const float c = cosf(fr), s = sinf(fr);
    float o0 = y0 * c - y1 * s;
    float o1 = y1 * c + y0 * s;
    if (isq) { o0 *= 0.08838834764831845f; o1 *= 0.08838834764831845f; }  // DH^-0.5
    p[lane] = f2bf(o0);
    p[lane + 64] = f2bf(o1);
}

// ---------------- sliding-window attention, 1 wave per query row ----------------
__global__ __launch_bounds__(256) void attn(const ush* __restrict__ q, const ush* __restrict__ k,
                                            const ush* __restrict__ v, ush* __restrict__ ctx)
{
    const int lane = threadIdx.x & 63;
    const int gr = blockIdx.x * 4 + (threadIdx.x >> 6);   // (b*H + h)*T + t
    const int b = gr >> 15;              // H*T = 32768
    const int rem = gr & 32767;
    const int h = rem >> 11;
    const int t = rem & (T_ - 1);
    const int hkv = h >> 1;              // G = 2

    const uint32_t qu = *reinterpret_cast<const uint32_t*>(q + ((size_t)gr << 7) + 2 * lane);
    const float qa = __uint_as_float((qu & 0xffffu) << 16);
    const float qb = __uint_as_float(qu & 0xffff0000u);

    const ush* kb_ = k + (((size_t)b * HKV_ + hkv) << 18);   // * T_*DH_
    const ush* vb_ = v + (((size_t)b * HKV_ + hkv) << 18);

    int t0 = t - WINDOW_; if (t0 < 0) t0 = 0;
    float m = -1e30f, lsum = 0.f, a0 = 0.f, a1 = 0.f;
    for (int tk = t0; tk <= t; ++tk) {
        const uint32_t ku = *reinterpret_cast<const uint32_t*>(kb_ + ((size_t)tk << 7) + 2 * lane);
        float s = qa * __uint_as_float((ku & 0xffffu) << 16)
                + qb * __uint_as_float(ku & 0xffff0000u);
#pragma unroll
        for (int off = 32; off; off >>= 1) s += __shfl_xor(s, off);
        const float nm = fmaxf(m, s);
        const float sc = __expf(m - nm);
        const float e = __expf(s - nm);
        lsum = lsum * sc + e;
        const uint32_t vu = *reinterpret_cast<const uint32_t*>(vb_ + ((size_t)tk << 7) + 2 * lane);
        a0 = a0 * sc + e * __uint_as_float((vu & 0xffffu) << 16);
        a1 = a1 * sc + e * __uint_as_float(vu & 0xffff0000u);
        m = nm;
    }
    const float inv = 1.0f / lsum;
    const ush o0 = f2bf(a0 * inv), o1 = f2bf(a1 * inv);
    const size_t cidx = (((size_t)b * T_ + t) * (H_ * DH_)) + (size_t)h * DH_ + 2 * lane;
    *reinterpret_cast<uint32_t*>(ctx + cidx) = (uint32_t)o0 | ((uint32_t)o1 << 16);
}

// ---------------- host launcher ----------------
extern "C" void kernel_launch(void* const* d_in, const int* in_sizes, int n_in,
                              void* d_out, int out_size, void* d_ws, size_t ws_size,
                              hipStream_t stream)
{
    const float* x   = (const float*)d_in[0];
    const float* wq  = (const float*)d_in[1];
    const float* wk  = (const float*)d_in[2];
    const float* wv  = (const float*)d_in[3];
    const float* wo  = (const float*)d_in[4];
    const float* qnw = (const float*)d_in[5];
    const float* knw = (const float*)d_in[6];
    float* out = (float*)d_out;

    // workspace layout (ush elements), total 88 MiB
    ush* ws    = (ush*)d_ws;
    ush* xbf   = ws;                      // [4096][2048]            16 MiB
    ush* wqkv  = xbf  + 8388608;          // [4096][2048] (wq;wk;wv) 16 MiB
    ush* wobf  = wqkv + 8388608;          // [2048][2048]             8 MiB
    ush* qraw  = wobf + 4194304;          // [B][H][T][DH]           16 MiB
    ush* kraw  = qraw + 8388608;          // [B][HKV][T][DH]          8 MiB
    ush* vraw  = kraw + 4194304;          // [B][HKV][T][DH]          8 MiB
    ush* ctx   = vraw + 4194304;          // [B][T][H*DH]            16 MiB

    cast_kernel<<<8192, 256, 0, stream>>>(x,  xbf, 2097152);
    cast_kernel<<<4096, 256, 0, stream>>>(wq, wqkv, 1048576);
    cast_kernel<<<2048, 256, 0, stream>>>(wk, wqkv + 4194304, 524288);
    cast_kernel<<<2048, 256, 0, stream>>>(wv, wqkv + 6291456, 524288);
    cast_kernel<<<4096, 256, 0, stream>>>(wo, wobf, 1048576);

    // QKV projection: M=4096 (b,t), N=4096 (q|k|v heads), K=2048
    gemm_bt<0><<<dim3(32, 32), 256, 0, stream>>>(xbf, wqkv, nullptr, qraw, kraw, vraw,
                                                 4096, 4096, 2048);
    // RMSNorm + RoPE on q (65536 rows) and k (32768 rows)
    norm_rope<<<(65536 + 32768) / 4, 256, 0, stream>>>(qraw, kraw, qnw, knw);
    // sliding-window attention
    attn<<<65536 / 4, 256, 0, stream>>>(qraw, kraw, vraw, ctx);
    // output projection: M=4096, N=2048, K=2048, fp32 out
    gemm_bt<1><<<dim3(32, 16), 256, 0, stream>>>(ctx, wobf, out, nullptr, nullptr, nullptr,
                                                 4096, 2048, 2048);
    (void)in_sizes; (void)n_in; (void)out_size; (void)ws_size;
}

// Round 3
// 260.421 us; speedup vs baseline: 8.1532x; 8.1532x over previous
//
#include <hip/hip_runtime.h>
#include <hip/hip_bf16.h>
#include <stdint.h>

#define B_ 2
#define T_ 2048
#define E_ 2048
#define H_ 16
#define HKV_ 8
#define DH_ 128
#define WINDOW_ 512

typedef unsigned short ush;
typedef float f32x4 __attribute__((ext_vector_type(4)));
typedef __bf16 bf16x8 __attribute__((ext_vector_type(8)));
typedef uint32_t u32x4 __attribute__((ext_vector_type(4)));

static __device__ __forceinline__ ush f2bf(float f) {
    uint32_t u = __float_as_uint(f);
    uint32_t r = (u + 0x7fffu + ((u >> 16) & 1u)) >> 16;
    return (ush)r;
}
static __device__ __forceinline__ float bf2f(ush h) {
    return __uint_as_float(((uint32_t)h) << 16);
}

// ---------------- fp32 -> bf16 cast (vectorized) ----------------
__global__ __launch_bounds__(256) void cast_kernel(const float* __restrict__ in,
                                                   ush* __restrict__ out, int n4) {
    int i = blockIdx.x * blockDim.x + threadIdx.x;
    if (i >= n4) return;
    float4 f = reinterpret_cast<const float4*>(in)[i];
    ushort4 o;
    o.x = f2bf(f.x); o.y = f2bf(f.y); o.z = f2bf(f.z); o.w = f2bf(f.w);
    reinterpret_cast<ushort4*>(out)[i] = o;
}

// ---------------- bf16 GEMM, C = A * B^T  (A:[M][K], Bm:[N][K]) ----------------
// MODE 0: scatter bf16 into q/k layouts + V TRANSPOSED (vT[b][hkv][d][t])
// MODE 1: fp32 row-major C[M][N]
template <int MODE>
__global__ __launch_bounds__(256, 2) void gemm_bt(
    const ush* __restrict__ A, const ush* __restrict__ Bm,
    float* __restrict__ Cf, ush* __restrict__ q, ush* __restrict__ k, ush* __restrict__ vT,
    int M, int N, int K)
{
    __shared__ ush As[128 * 64];
    __shared__ ush Bs[128 * 64];
    const int tid = threadIdx.x;
    const int lane = tid & 63;
    const int wid = tid >> 6;
    const int wr = wid >> 1, wc = wid & 1;
    const int gm0 = blockIdx.x * 128, gn0 = blockIdx.y * 128;

    f32x4 acc[4][4] = {};

    const int l8 = lane >> 3;
    const int ce = (lane & 7) * 8;

    for (int kt = 0; kt < K; kt += 64) {
#pragma unroll
        for (int i = 0; i < 4; ++i) {
            const int rowbase = (i * 4 + wid) * 8;
            const int ra = rowbase + l8;
            const ush* ga = A + (size_t)(gm0 + ra) * K + kt + ce;
            __builtin_amdgcn_global_load_lds(
                (const __attribute__((address_space(1))) void*)ga,
                (__attribute__((address_space(3))) void*)(As + rowbase * 64), 16, 0, 0);
            const ush* gb = Bm + (size_t)(gn0 + ra) * K + kt + ce;
            __builtin_amdgcn_global_load_lds(
                (const __attribute__((address_space(1))) void*)gb,
                (__attribute__((address_space(3))) void*)(Bs + rowbase * 64), 16, 0, 0);
        }
        __syncthreads();

#pragma unroll
        for (int s = 0; s < 2; ++s) {
            bf16x8 aF[4], bF[4];
#pragma unroll
            for (int mm = 0; mm < 4; ++mm) {
                int r = wr * 64 + mm * 16 + (lane & 15);
                aF[mm] = *reinterpret_cast<const bf16x8*>(As + r * 64 + s * 32 + ((lane >> 4) * 8));
            }
#pragma unroll
            for (int nn = 0; nn < 4; ++nn) {
                int r = wc * 64 + nn * 16 + (lane & 15);
                bF[nn] = *reinterpret_cast<const bf16x8*>(Bs + r * 64 + s * 32 + ((lane >> 4) * 8));
            }
#pragma unroll
            for (int mm = 0; mm < 4; ++mm)
#pragma unroll
                for (int nn = 0; nn < 4; ++nn)
                    acc[mm][nn] = __builtin_amdgcn_mfma_f32_16x16x32_bf16(
                        aF[mm], bF[nn], acc[mm][nn], 0, 0, 0);
        }
        __syncthreads();
    }

    const int rsub = (lane >> 4) << 2;
    const int csub = lane & 15;
#pragma unroll
    for (int mm = 0; mm < 4; ++mm) {
        const int row0 = gm0 + wr * 64 + mm * 16 + rsub;
#pragma unroll
        for (int nn = 0; nn < 4; ++nn) {
            const int col = gn0 + wc * 64 + nn * 16 + csub;
#pragma unroll
            for (int r = 0; r < 4; ++r) {
                const int row = row0 + r;
                if (MODE == 1) {
                    Cf[(size_t)row * N + col] = acc[mm][nn][r];
                } else {
                    const int bb = row >> 11, tt = row & (T_ - 1);
                    const ush val = f2bf(acc[mm][nn][r]);
                    if (col < H_ * DH_) {
                        const int hh = col >> 7, d = col & 127;
                        q[((((size_t)bb * H_ + hh) * T_ + tt) << 7) + d] = val;
                    } else if (col < H_ * DH_ + HKV_ * DH_) {
                        const int c2 = col - H_ * DH_;
                        const int hh = c2 >> 7, d = c2 & 127;
                        k[((((size_t)bb * HKV_ + hh) * T_ + tt) << 7) + d] = val;
                    } else {
                        const int c2 = col - H_ * DH_ - HKV_ * DH_;
                        const int hh = c2 >> 7, d = c2 & 127;
                        // V transposed: vT[((b*HKV+hh)*128 + d)][t]
                        vT[((size_t)((bb * HKV_ + hh) * DH_ + d) << 11) + tt] = val;
                    }
                }
            }
        }
    }
}

// ---------------- per-head RMSNorm + RoPE (+ q scale), in place ----------------
__global__ __launch_bounds__(256) void norm_rope(ush* __restrict__ q, ush* __restrict__ k,
                                                 const float* __restrict__ qw,
                                                 const float* __restrict__ kw)
{
    const int lane = threadIdx.x & 63;
    const int row = blockIdx.x * 4 + (threadIdx.x >> 6);
    const int NQ = B_ * H_ * T_;
    ush* p; const float* w; int t; bool isq = (row < NQ);
    if (isq) { p = q + ((size_t)row << 7); t = row & (T_ - 1); w = qw; }
    else     { int r2 = row - NQ; p = k + ((size_t)r2 << 7); t = r2 & (T_ - 1); w = kw; }

    float x0 = bf2f(p[lane]);
    float x1 = bf2f(p[lane + 64]);
    float ss = x0 * x0 + x1 * x1;
#pragma unroll
    for (int off = 32; off; off >>= 1) ss += __shfl_xor(ss, off);
    const float rms = rsqrtf(ss * (1.0f / 128.0f) + 1e-6f);
    float y0 = x0 * rms * (1.0f + w[lane]);
    float y1 = x1 * rms * (1.0f + w[lane + 64]);

    const float invf = expf(-(float)lane * 0.14391156831212787f);
    const float fr = (float)t * invf;
    const float c = cosf(fr), s = sinf(fr);
    float o0 = y0 * c - y1 * s;
    float o1 = y1 * c + y0 * s;
    if (isq) { o0 *= 0.08838834764831845f; o1 *= 0.08838834764831845f; }
    p[lane] = f2bf(o0);
    p[lane + 64] = f2bf(o1);
}

// ---------------- MFMA flash attention (sliding window), builtin-only ----------------
// block = 64 queries of one (b,h); 4 waves x 16 queries; 32-key tiles, dbuf LDS.
// QK^T (swapped): S^T = mfma_16x16x32(K_frag, Q_frag); lane(g,t) holds
// S[key=kt0+16s+4g+r][q=qb+16w+t] for s=0,1, r=0..3.
// PV as O^T = V^T * P^T with ONE K=32 mfma per 16-d block:
//   A-frag = V^T[d=16ds+t][key=8g+e]  <- contiguous ds_read_b128 from VT tile
//   B-frag = P^T[key=8g+e][q=t]       <- 8 __shfl redistribution from S^T words
// O^T output: o[ds][r] = O[q=t][d=16ds+4g+r]; softmax state is lane-local in q=t.
__global__ __launch_bounds__(256) void attn_mfma(const ush* __restrict__ q,
        const ush* __restrict__ k, const ush* __restrict__ vT, ush* __restrict__ ctx)
{
    __shared__ ush Ks[2][32 * 128];   // [key][d] linear (swizzle deferred)
    __shared__ ush Vs[2][128 * 32];   // [d][key] (V^T tile), 64B rows
    const int tid = threadIdx.x;
    const int lane = tid & 63;
    const int w = tid >> 6;
    const int g = lane >> 4;
    const int t = lane & 15;

    int bi = blockIdx.x;
    bi = (bi & 7) * 128 + (bi >> 3);               // XCD swizzle (1024 % 8 == 0)
    const int qtile = bi & 31;
    const int hh = (bi >> 5) & 15;
    const int b = bi >> 9;
    const int qb = qtile * 64;
    const int hkv = hh >> 1;

    const ush* qptr = q + ((((size_t)b * H_ + hh) * T_ + qb) << 7);
    const ush* kbase = k + (((size_t)b * HKV_ + hkv) << 18);     // *T*DH
    const ush* vtbase = vT + (((size_t)b * HKV_ + hkv) << 18);   // *DH*T

    // Q fragments (B-operand of swapped QK^T): Q[q=16w+t][d=32c+8g..+7]
    bf16x8 qf[4];
#pragma unroll
    for (int c = 0; c < 4; ++c)
        qf[c] = *reinterpret_cast<const bf16x8*>(qptr + ((16 * w + t) << 7) + 32 * c + 8 * g);

    const int kstart = (qb >= WINDOW_) ? (qb - WINDOW_) : 0;
    const int nt = (qb + 64 - kstart) >> 5;

    auto stage = [&](int ti, int buf) {
        const int kt0 = kstart + (ti << 5);
#pragma unroll
        for (int i = 0; i < 2; ++i) {
            const int C = w * 128 + i * 64 + lane;      // 16B chunk id, 0..511
            {   // K tile: [32 keys][128 d] linear
                const int row = C >> 4, ch = C & 15;
                const ush* gk = kbase + ((size_t)(kt0 + row) << 7) + ch * 8;
                __builtin_amdgcn_global_load_lds(
                    (const __attribute__((address_space(1))) void*)gk,
                    (__attribute__((address_space(3))) void*)(&Ks[buf][(w * 128 + i * 64) * 8]),
                    16, 0, 0);
            }
            {   // V^T tile: [128 d][32 keys], src rows stride T_
                const int row = C >> 2, ch = C & 3;
                const ush* gv = vtbase + ((size_t)row << 11) + kt0 + ch * 8;
                __builtin_amdgcn_global_load_lds(
                    (const __attribute__((address_space(1))) void*)gv,
                    (__attribute__((address_space(3))) void*)(&Vs[buf][(w * 128 + i * 64) * 8]),
                    16, 0, 0);
            }
        }
    };

    float m = -1e30f, lsum = 0.f;
    f32x4 o[8] = {};

    stage(0, 0);
    __syncthreads();

    for (int ti = 0; ti < nt; ++ti) {
        const int cur = ti & 1;
        if (ti + 1 < nt) stage(ti + 1, cur ^ 1);
        const int kt0 = kstart + (ti << 5);
        const int qw0 = qb + 16 * w;
        const bool active = (kt0 + 31 >= qw0 - WINDOW_) && (kt0 <= qw0 + 15);
        if (active) {
            // ---- QK^T ----
            f32x4 st[2] = {};
#pragma unroll
            for (int s = 0; s < 2; ++s)
#pragma unroll
                for (int c = 0; c < 4; ++c) {
                    bf16x8 kf = *reinterpret_cast<const bf16x8*>(
                        &Ks[cur][(16 * s + t) * 128 + 32 * c + 8 * g]);
                    st[s] = __builtin_amdgcn_mfma_f32_16x16x32_bf16(kf, qf[c], st[s], 0, 0, 0);
                }
            // ---- mask + online softmax (state lane-local in q=t) ----
            const int tg = qb + 16 * w + t;
            float e[2][4];
            float mymax = -3e38f;
#pragma unroll
            for (int s = 0; s < 2; ++s)
#pragma unroll
                for (int r = 0; r < 4; ++r) {
                    const int key = kt0 + 16 * s + 4 * g + r;
                    const int dist = tg - key;
                    const bool valid = (dist >= 0) && (dist <= WINDOW_);
                    const float sv = valid ? st[s][r] : -3e38f;
                    e[s][r] = sv;
                    mymax = fmaxf(mymax, sv);
                }
            mymax = fmaxf(mymax, __shfl_xor(mymax, 16));
            mymax = fmaxf(mymax, __shfl_xor(mymax, 32));
            const float mn = fmaxf(m, mymax);
            const float sc = __expf(m - mn);
            float esum = 0.f;
#pragma unroll
            for (int s = 0; s < 2; ++s)
#pragma unroll
                for (int r = 0; r < 4; ++r) {
                    const float ev = __expf(e[s][r] - mn);
                    e[s][r] = ev;
                    esum += ev;
                }
            esum += __shfl_xor(esum, 16);
            esum += __shfl_xor(esum, 32);
            lsum = lsum * sc + esum;
            m = mn;
            // ---- rescale O (lane-local sc) ----
#pragma unroll
            for (int ds = 0; ds < 8; ++ds) {
                o[ds][0] *= sc; o[ds][1] *= sc; o[ds][2] *= sc; o[ds][3] *= sc;
            }
            // ---- pack P to bf16 words: word[s][wd] = keys {16s+4g+2wd, +1} of q=t ----
            uint32_t word[2][2];
#pragma unroll
            for (int s = 0; s < 2; ++s)
#pragma unroll
                for (int wd = 0; wd < 2; ++wd)
                    word[s][wd] = (uint32_t)f2bf(e[s][2 * wd])
                                | ((uint32_t)f2bf(e[s][2 * wd + 1]) << 16);
            // ---- redistribute to P^T B-frag: lane(g,t) needs keys 8g..8g+7 of q=t.
            // dest word e2 (keys 8g+2e2,+1) comes from src lane (a=2(g&1)+(e2>>1), t),
            // sub-tile s'=g>>1, word (e2&1). Shuffle both s' words, select by g.
            u32x4 bw;
#pragma unroll
            for (int e2 = 0; e2 < 4; ++e2) {
                const int srcl = 16 * (2 * (g & 1) + (e2 >> 1)) + t;
                const uint32_t v0 = __shfl(word[0][e2 & 1], srcl);
                const uint32_t v1 = __shfl(word[1][e2 & 1], srcl);
                bw[e2] = (g >= 2) ? v1 : v0;
            }
            const bf16x8 pF = __builtin_bit_cast(bf16x8, bw);
            // ---- PV: O^T += V^T * P^T, one K=32 mfma per 16-d block ----
#pragma unroll
            for (int ds = 0; ds < 8; ++ds) {
                bf16x8 vtF = *reinterpret_cast<const bf16x8*>(
                    &Vs[cur][(16 * ds + t) * 32 + 8 * g]);
                o[ds] = __builtin_amdgcn_mfma_f32_16x16x32_bf16(vtF, pF, o[ds], 0, 0, 0);
            }
        }
        __syncthreads();
    }

    const float linv = 1.0f / lsum;      // lane-local (q=t)
    ush* cptr = ctx + (((size_t)b * T_ + qb + 16 * w + t) * (H_ * DH_)) + hh * DH_;
#pragma unroll
    for (int ds = 0; ds < 8; ++ds) {
        ushort4 pk;
        pk.x = f2bf(o[ds][0] * linv);
        pk.y = f2bf(o[ds][1] * linv);
        pk.z = f2bf(o[ds][2] * linv);
        pk.w = f2bf(o[ds][3] * linv);
        *reinterpret_cast<ushort4*>(cptr + 16 * ds + 4 * g) = pk;   // d = 16ds+4g..+3
    }
}

// ---------------- host launcher ----------------
extern "C" void kernel_launch(void* const* d_in, const int* in_sizes, int n_in,
                              void* d_out, int out_size, void* d_ws, size_t ws_size,
                              hipStream_t stream)
{
    const float* x   = (const float*)d_in[0];
    const float* wq  = (const float*)d_in[1];
    const float* wk  = (const float*)d_in[2];
    const float* wv  = (const float*)d_in[3];
    const float* wo  = (const float*)d_in[4];
    const float* qnw = (const float*)d_in[5];
    const float* knw = (const float*)d_in[6];
    float* out = (float*)d_out;

    ush* ws    = (ush*)d_ws;
    ush* xbf   = ws;                      // [4096][2048]
    ush* wqkv  = xbf  + 8388608;          // [4096][2048]
    ush* wobf  = wqkv + 8388608;          // [2048][2048]
    ush* qraw  = wobf + 4194304;          // [B][H][T][DH]
    ush* kraw  = qraw + 8388608;          // [B][HKV][T][DH]
    ush* vTb   = kraw + 4194304;          // [B][HKV][DH][T]  (transposed V)
    ush* ctx   = vTb  + 4194304;          // [B][T][H*DH]

    cast_kernel<<<8192, 256, 0, stream>>>(x,  xbf, 2097152);
    cast_kernel<<<4096, 256, 0, stream>>>(wq, wqkv, 1048576);
    cast_kernel<<<2048, 256, 0, stream>>>(wk, wqkv + 4194304, 524288);
    cast_kernel<<<2048, 256, 0, stream>>>(wv, wqkv + 6291456, 524288);
    cast_kernel<<<4096, 256, 0, stream>>>(wo, wobf, 1048576);

    gemm_bt<0><<<dim3(32, 32), 256, 0, stream>>>(xbf, wqkv, nullptr, qraw, kraw, vTb,
                                                 4096, 4096, 2048);
    norm_rope<<<(65536 + 32768) / 4, 256, 0, stream>>>(qraw, kraw, qnw, knw);
    attn_mfma<<<1024, 256, 0, stream>>>(qraw, kraw, vTb, ctx);
    gemm_bt<1><<<dim3(32, 16), 256, 0, stream>>>(ctx, wobf, out, nullptr, nullptr, nullptr,
                                                 4096, 2048, 2048);
    (void)in_sizes; (void)n_in; (void)out_size; (void)ws_size;
}

// Round 4
// 232.671 us; speedup vs baseline: 9.1257x; 1.1193x over previous
//
#include <hip/hip_runtime.h>
#include <hip/hip_bf16.h>
#include <stdint.h>

#define B_ 2
#define T_ 2048
#define E_ 2048
#define H_ 16
#define HKV_ 8
#define DH_ 128
#define WINDOW_ 512

typedef unsigned short ush;
typedef float f32x4 __attribute__((ext_vector_type(4)));
typedef __bf16 bf16x8 __attribute__((ext_vector_type(8)));
typedef uint32_t u32x4 __attribute__((ext_vector_type(4)));

static __device__ __forceinline__ ush f2bf(float f) {
    uint32_t u = __float_as_uint(f);
    uint32_t r = (u + 0x7fffu + ((u >> 16) & 1u)) >> 16;
    return (ush)r;
}
static __device__ __forceinline__ float bf2f(ush h) {
    return __uint_as_float(((uint32_t)h) << 16);
}

// ---------------- fp32 -> bf16 cast (vectorized) ----------------
__global__ __launch_bounds__(256) void cast_kernel(const float* __restrict__ in,
                                                   ush* __restrict__ out, int n4) {
    int i = blockIdx.x * blockDim.x + threadIdx.x;
    if (i >= n4) return;
    float4 f = reinterpret_cast<const float4*>(in)[i];
    ushort4 o;
    o.x = f2bf(f.x); o.y = f2bf(f.y); o.z = f2bf(f.z); o.w = f2bf(f.w);
    reinterpret_cast<ushort4*>(out)[i] = o;
}

// ---------------- bf16 GEMM v2: 128x256 tile, 8 waves, triple-buffer, counted vmcnt ----
// C = A * B^T (A:[M][K], Bm:[N][K]). T2 chunk-swizzle (c ^= row&7) both sides.
// Race-free invariant: stage(kt) issues during kt-2 into buf[kt%3]; buf's prior
// tile (kt-3) reads ended at kt-3's end-barrier (lgkm drained before each wave's
// MFMA -> barrier). vmcnt(6) at end of kt-1 confirms kt resident; barrier publishes.
template <int MODE>
__global__ __launch_bounds__(512, 2) void gemm_bt2(
    const ush* __restrict__ A, const ush* __restrict__ Bm,
    float* __restrict__ Cf, ush* __restrict__ q, ush* __restrict__ k, ush* __restrict__ vT,
    int M, int N, int K)
{
    __shared__ ush As[3][128 * 64];   // 48 KiB
    __shared__ ush Bs[3][256 * 64];   // 96 KiB
    const int tid = threadIdx.x;
    const int lane = tid & 63;
    const int wid = tid >> 6;            // 0..7
    const int wr = wid >> 2, wc = wid & 3;  // wave M-half (0..1), N-quarter (0..3)
    const int g = lane >> 4, t = lane & 15;
    const int gm0 = blockIdx.x * 128, gn0 = blockIdx.y * 256;

    f32x4 acc[4][4] = {};   // [mf][nf], per-wave 64x64 output

    // ---- staging helpers: chunk (r,c) of LDS holds global chunk (r, c^(r&7)) ----
    auto stageA2 = [&](int kt, int m3) {      // 2 loads
#pragma unroll
        for (int i = 0; i < 2; ++i) {
            const int C = i * 512 + tid;
            const int r = C >> 3, c = C & 7;
            const ush* src = A + (size_t)(gm0 + r) * K + (kt << 6) + ((c ^ (r & 7)) << 3);
            __builtin_amdgcn_global_load_lds(
                (const __attribute__((address_space(1))) void*)src,
                (__attribute__((address_space(3))) void*)(&As[m3][C << 3]), 16, 0, 0);
        }
    };
    auto stageB = [&](int kt, int m3, int i0, int i1) {   // loads i0..i1-1
        for (int i = i0; i < i1; ++i) {
            const int C = i * 512 + tid;
            const int r = C >> 3, c = C & 7;
            const ush* src = Bm + (size_t)(gn0 + r) * K + (kt << 6) + ((c ^ (r & 7)) << 3);
            __builtin_amdgcn_global_load_lds(
                (const __attribute__((address_space(1))) void*)src,
                (__attribute__((address_space(3))) void*)(&Bs[m3][C << 3]), 16, 0, 0);
        }
    };

    const int nt = K >> 6;   // assumed >= 2

    // ---- prologue: stage tiles 0 and 1 (6 loads each), wait tile 0 ----
    stageA2(0, 0); stageB(0, 0, 0, 4);
    stageA2(1, 1); stageB(1, 1, 0, 4);
    asm volatile("s_waitcnt vmcnt(6)" ::: "memory");   // oldest 6 = tile 0 done
    __builtin_amdgcn_s_barrier();
    __builtin_amdgcn_sched_barrier(0);

    int m3 = 0;
    for (int kt = 0; kt < nt; ++kt) {
        const int st3 = (m3 + 2 >= 3) ? m3 - 1 : m3 + 2;   // (kt+2)%3
        bf16x8 af[4][2], bfr[2][2];

        // ======== phase 0: A-frags + B-quad0 reads, 3 issues, MFMA quad 0 ========
#pragma unroll
        for (int mf = 0; mf < 4; ++mf)
#pragma unroll
            for (int ks = 0; ks < 2; ++ks) {
                const int row = wr * 64 + mf * 16 + t;
                af[mf][ks] = *reinterpret_cast<const bf16x8*>(
                    &As[m3][row * 64 + ((((ks << 2) + g) ^ (t & 7)) << 3)]);
            }
#pragma unroll
        for (int n2 = 0; n2 < 2; ++n2)
#pragma unroll
            for (int ks = 0; ks < 2; ++ks) {
                const int row = wc * 64 + n2 * 16 + t;
                bfr[n2][ks] = *reinterpret_cast<const bf16x8*>(
                    &Bs[m3][row * 64 + ((((ks << 2) + g) ^ (t & 7)) << 3)]);
            }
        if (kt + 2 < nt) { stageA2(kt + 2, st3); stageB(kt + 2, st3, 0, 1); }
        __builtin_amdgcn_s_setprio(1);
#pragma unroll
        for (int mf = 0; mf < 4; ++mf)
#pragma unroll
            for (int n2 = 0; n2 < 2; ++n2)
#pragma unroll
                for (int ks = 0; ks < 2; ++ks)
                    acc[mf][n2] = __builtin_amdgcn_mfma_f32_16x16x32_bf16(
                        af[mf][ks], bfr[n2][ks], acc[mf][n2], 0, 0, 0);
        __builtin_amdgcn_s_setprio(0);
        __builtin_amdgcn_s_barrier();
        __builtin_amdgcn_sched_barrier(0);

        // ======== phase 1: B-quad1 reads, 3 issues, MFMA quad 1, vmcnt, barrier ====
#pragma unroll
        for (int n2 = 0; n2 < 2; ++n2)
#pragma unroll
            for (int ks = 0; ks < 2; ++ks) {
                const int row = wc * 64 + (2 + n2) * 16 + t;
                bfr[n2][ks] = *reinterpret_cast<const bf16x8*>(
                    &Bs[m3][row * 64 + ((((ks << 2) + g) ^ (t & 7)) << 3)]);
            }
        if (kt + 2 < nt) stageB(kt + 2, st3, 1, 4);
        __builtin_amdgcn_s_setprio(1);
#pragma unroll
        for (int mf = 0; mf < 4; ++mf)
#pragma unroll
            for (int n2 = 0; n2 < 2; ++n2)
#pragma unroll
                for (int ks = 0; ks < 2; ++ks)
                    acc[mf][2 + n2] = __builtin_amdgcn_mfma_f32_16x16x32_bf16(
                        af[mf][ks], bfr[n2][ks], acc[mf][2 + n2], 0, 0, 0);
        __builtin_amdgcn_s_setprio(0);
        if (kt + 1 < nt) {
            if (kt + 2 < nt) asm volatile("s_waitcnt vmcnt(6)" ::: "memory");
            else             asm volatile("s_waitcnt vmcnt(0)" ::: "memory");
        }
        __builtin_amdgcn_s_barrier();
        __builtin_amdgcn_sched_barrier(0);

        m3 = (m3 + 1 >= 3) ? 0 : m3 + 1;
    }

    // ---- epilogue: C/D layout col=lane&15, row=4*(lane>>4)+r ----
    const int rsub = (lane >> 4) << 2;
    const int csub = lane & 15;
#pragma unroll
    for (int mf = 0; mf < 4; ++mf) {
        const int row0 = gm0 + wr * 64 + mf * 16 + rsub;
#pragma unroll
        for (int nf = 0; nf < 4; ++nf) {
            const int col = gn0 + wc * 64 + nf * 16 + csub;
#pragma unroll
            for (int r = 0; r < 4; ++r) {
                const int row = row0 + r;
                if (MODE == 1) {
                    Cf[(size_t)row * N + col] = acc[mf][nf][r];
                } else {
                    const int bb = row >> 11, tt = row & (T_ - 1);
                    const ush val = f2bf(acc[mf][nf][r]);
                    if (col < H_ * DH_) {
                        const int hh = col >> 7, d = col & 127;
                        q[((((size_t)bb * H_ + hh) * T_ + tt) << 7) + d] = val;
                    } else if (col < H_ * DH_ + HKV_ * DH_) {
                        const int c2 = col - H_ * DH_;
                        const int hh = c2 >> 7, d = c2 & 127;
                        k[((((size_t)bb * HKV_ + hh) * T_ + tt) << 7) + d] = val;
                    } else {
                        const int c2 = col - H_ * DH_ - HKV_ * DH_;
                        const int hh = c2 >> 7, d = c2 & 127;
                        vT[((size_t)((bb * HKV_ + hh) * DH_ + d) << 11) + tt] = val;
                    }
                }
            }
        }
    }
}

// ---------------- per-head RMSNorm + RoPE (+ q scale), in place ----------------
__global__ __launch_bounds__(256) void norm_rope(ush* __restrict__ q, ush* __restrict__ k,
                                                 const float* __restrict__ qw,
                                                 const float* __restrict__ kw)
{
    const int lane = threadIdx.x & 63;
    const int row = blockIdx.x * 4 + (threadIdx.x >> 6);
    const int NQ = B_ * H_ * T_;
    ush* p; const float* w; int t; bool isq = (row < NQ);
    if (isq) { p = q + ((size_t)row << 7); t = row & (T_ - 1); w = qw; }
    else     { int r2 = row - NQ; p = k + ((size_t)r2 << 7); t = r2 & (T_ - 1); w = kw; }

    float x0 = bf2f(p[lane]);
    float x1 = bf2f(p[lane + 64]);
    float ss = x0 * x0 + x1 * x1;
#pragma unroll
    for (int off = 32; off; off >>= 1) ss += __shfl_xor(ss, off);
    const float rms = rsqrtf(ss * (1.0f / 128.0f) + 1e-6f);
    float y0 = x0 * rms * (1.0f + w[lane]);
    float y1 = x1 * rms * (1.0f + w[lane + 64]);

    const float invf = expf(-(float)lane * 0.14391156831212787f);
    const float fr = (float)t * invf;
    const float c = cosf(fr), s = sinf(fr);
    float o0 = y0 * c - y1 * s;
    float o1 = y1 * c + y0 * s;
    if (isq) { o0 *= 0.08838834764831845f; o1 *= 0.08838834764831845f; }
    p[lane] = f2bf(o0);
    p[lane + 64] = f2bf(o1);
}

// ---------------- MFMA flash attention (sliding window), builtin-only ----------------
__global__ __launch_bounds__(256) void attn_mfma(const ush* __restrict__ q,
        const ush* __restrict__ k, const ush* __restrict__ vT, ush* __restrict__ ctx)
{
    __shared__ ush Ks[2][32 * 128];   // [key][d] linear
    __shared__ ush Vs[2][128 * 32];   // [d][key] (V^T tile)
    const int tid = threadIdx.x;
    const int lane = tid & 63;
    const int w = tid >> 6;
    const int g = lane >> 4;
    const int t = lane & 15;

    int bi = blockIdx.x;
    bi = (bi & 7) * 128 + (bi >> 3);
    const int qtile = bi & 31;
    const int hh = (bi >> 5) & 15;
    const int b = bi >> 9;
    const int qb = qtile * 64;
    const int hkv = hh >> 1;

    const ush* qptr = q + ((((size_t)b * H_ + hh) * T_ + qb) << 7);
    const ush* kbase = k + (((size_t)b * HKV_ + hkv) << 18);
    const ush* vtbase = vT + (((size_t)b * HKV_ + hkv) << 18);

    bf16x8 qf[4];
#pragma unroll
    for (int c = 0; c < 4; ++c)
        qf[c] = *reinterpret_cast<const bf16x8*>(qptr + ((16 * w + t) << 7) + 32 * c + 8 * g);

    const int kstart = (qb >= WINDOW_) ? (qb - WINDOW_) : 0;
    const int nt = (qb + 64 - kstart) >> 5;

    auto stage = [&](int ti, int buf) {
        const int kt0 = kstart + (ti << 5);
#pragma unroll
        for (int i = 0; i < 2; ++i) {
            const int C = w * 128 + i * 64 + lane;
            {
                const int row = C >> 4, ch = C & 15;
                const ush* gk = kbase + ((size_t)(kt0 + row) << 7) + ch * 8;
                __builtin_amdgcn_global_load_lds(
                    (const __attribute__((address_space(1))) void*)gk,
                    (__attribute__((address_space(3))) void*)(&Ks[buf][(w * 128 + i * 64) * 8]),
                    16, 0, 0);
            }
            {
                const int row = C >> 2, ch = C & 3;
                const ush* gv = vtbase + ((size_t)row << 11) + kt0 + ch * 8;
                __builtin_amdgcn_global_load_lds(
                    (const __attribute__((address_space(1))) void*)gv,
                    (__attribute__((address_space(3))) void*)(&Vs[buf][(w * 128 + i * 64) * 8]),
                    16, 0, 0);
            }
        }
    };

    float m = -1e30f, lsum = 0.f;
    f32x4 o[8] = {};

    stage(0, 0);
    __syncthreads();

    for (int ti = 0; ti < nt; ++ti) {
        const int cur = ti & 1;
        if (ti + 1 < nt) stage(ti + 1, cur ^ 1);
        const int kt0 = kstart + (ti << 5);
        const int qw0 = qb + 16 * w;
        const bool active = (kt0 + 31 >= qw0 - WINDOW_) && (kt0 <= qw0 + 15);
        if (active) {
            f32x4 st[2] = {};
#pragma unroll
            for (int s = 0; s < 2; ++s)
#pragma unroll
                for (int c = 0; c < 4; ++c) {
                    bf16x8 kf = *reinterpret_cast<const bf16x8*>(
                        &Ks[cur][(16 * s + t) * 128 + 32 * c + 8 * g]);
                    st[s] = __builtin_amdgcn_mfma_f32_16x16x32_bf16(kf, qf[c], st[s], 0, 0, 0);
                }
            const int tg = qb + 16 * w + t;
            float e[2][4];
            float mymax = -3e38f;
#pragma unroll
            for (int s = 0; s < 2; ++s)
#pragma unroll
                for (int r = 0; r < 4; ++r) {
                    const int key = kt0 + 16 * s + 4 * g + r;
                    const int dist = tg - key;
                    const bool valid = (dist >= 0) && (dist <= WINDOW_);
                    const float sv = valid ? st[s][r] : -3e38f;
                    e[s][r] = sv;
                    mymax = fmaxf(mymax, sv);
                }
            mymax = fmaxf(mymax, __shfl_xor(mymax, 16));
            mymax = fmaxf(mymax, __shfl_xor(mymax, 32));
            const float mn = fmaxf(m, mymax);
            const float sc = __expf(m - mn);
            float esum = 0.f;
#pragma unroll
            for (int s = 0; s < 2; ++s)
#pragma unroll
                for (int r = 0; r < 4; ++r) {
                    const float ev = __expf(e[s][r] - mn);
                    e[s][r] = ev;
                    esum += ev;
                }
            esum += __shfl_xor(esum, 16);
            esum += __shfl_xor(esum, 32);
            lsum = lsum * sc + esum;
            m = mn;
#pragma unroll
            for (int ds = 0; ds < 8; ++ds) {
                o[ds][0] *= sc; o[ds][1] *= sc; o[ds][2] *= sc; o[ds][3] *= sc;
            }
            uint32_t word[2][2];
#pragma unroll
            for (int s = 0; s < 2; ++s)
#pragma unroll
                for (int wd = 0; wd < 2; ++wd)
                    word[s][wd] = (uint32_t)f2bf(e[s][2 * wd])
                                | ((uint32_t)f2bf(e[s][2 * wd + 1]) << 16);
            u32x4 bw;
#pragma unroll
            for (int e2 = 0; e2 < 4; ++e2) {
                const int srcl = 16 * (2 * (g & 1) + (e2 >> 1)) + t;
                const uint32_t v0 = __shfl(word[0][e2 & 1], srcl);
                const uint32_t v1 = __shfl(word[1][e2 & 1], srcl);
                bw[e2] = (g >= 2) ? v1 : v0;
            }
            const bf16x8 pF = __builtin_bit_cast(bf16x8, bw);
#pragma unroll
            for (int ds = 0; ds < 8; ++ds) {
                bf16x8 vtF = *reinterpret_cast<const bf16x8*>(
                    &Vs[cur][(16 * ds + t) * 32 + 8 * g]);
                o[ds] = __builtin_amdgcn_mfma_f32_16x16x32_bf16(vtF, pF, o[ds], 0, 0, 0);
            }
        }
        __syncthreads();
    }

    const float linv = 1.0f / lsum;
    ush* cptr = ctx + (((size_t)b * T_ + qb + 16 * w + t) * (H_ * DH_)) + hh * DH_;
#pragma unroll
    for (int ds = 0; ds < 8; ++ds) {
        ushort4 pk;
        pk.x = f2bf(o[ds][0] * linv);
        pk.y = f2bf(o[ds][1] * linv);
        pk.z = f2bf(o[ds][2] * linv);
        pk.w = f2bf(o[ds][3] * linv);
        *reinterpret_cast<ushort4*>(cptr + 16 * ds + 4 * g) = pk;
    }
}

// ---------------- host launcher ----------------
extern "C" void kernel_launch(void* const* d_in, const int* in_sizes, int n_in,
                              void* d_out, int out_size, void* d_ws, size_t ws_size,
                              hipStream_t stream)
{
    const float* x   = (const float*)d_in[0];
    const float* wq  = (const float*)d_in[1];
    const float* wk  = (const float*)d_in[2];
    const float* wv  = (const float*)d_in[3];
    const float* wo  = (const float*)d_in[4];
    const float* qnw = (const float*)d_in[5];
    const float* knw = (const float*)d_in[6];
    float* out = (float*)d_out;

    ush* ws    = (ush*)d_ws;
    ush* xbf   = ws;                      // [4096][2048]
    ush* wqkv  = xbf  + 8388608;          // [4096][2048]
    ush* wobf  = wqkv + 8388608;          // [2048][2048]
    ush* qraw  = wobf + 4194304;          // [B][H][T][DH]
    ush* kraw  = qraw + 8388608;          // [B][HKV][T][DH]
    ush* vTb   = kraw + 4194304;          // [B][HKV][DH][T]
    ush* ctx   = vTb  + 4194304;          // [B][T][H*DH]

    cast_kernel<<<8192, 256, 0, stream>>>(x,  xbf, 2097152);
    cast_kernel<<<4096, 256, 0, stream>>>(wq, wqkv, 1048576);
    cast_kernel<<<2048, 256, 0, stream>>>(wk, wqkv + 4194304, 524288);
    cast_kernel<<<2048, 256, 0, stream>>>(wv, wqkv + 6291456, 524288);
    cast_kernel<<<4096, 256, 0, stream>>>(wo, wobf, 1048576);

    gemm_bt2<0><<<dim3(32, 16), 512, 0, stream>>>(xbf, wqkv, nullptr, qraw, kraw, vTb,
                                                  4096, 4096, 2048);
    norm_rope<<<(65536 + 32768) / 4, 256, 0, stream>>>(qraw, kraw, qnw, knw);
    attn_mfma<<<1024, 256, 0, stream>>>(qraw, kraw, vTb, ctx);
    gemm_bt2<1><<<dim3(32, 8), 512, 0, stream>>>(ctx, wobf, out, nullptr, nullptr, nullptr,
                                                 4096, 2048, 2048);
    (void)in_sizes; (void)n_in; (void)out_size; (void)ws_size;
}